// Round 6
// baseline (429.911 us; speedup 1.0000x reference)
//
#include <hip/hip_runtime.h>

// Atom_embedding_MP: B=4, N=100000, K=16, D=6, C_IN=13, 3 layers.
// Round-6: FOUR threads per point, NO LDS, pure register dataflow.
//  - R5 post-mortem: 59 KB LDS -> 2 blocks/CU -> 20% occupancy, VALUBusy 50%.
//    LDS bytes/point caps resident points; more threads/point is the only
//    way to more waves. At 4 thr/pt each thread owns just 28 input floats
//    (4 neighbors x 6 feats + 4 dists) -> register-resident trivially.
//  - fp32 pipe fact (corrects R4/R5 premise): scalar v_fma_f32 already
//    saturates 157 TF; v_pk_fma_f32 adds no FLOPs. Scalar FMA everywhere.
//  - __launch_bounds__(256,5): VGPR cap 102 (est. live ~85) -> 5 waves/SIMD,
//    no spill exposure. Only layer-loop memory ops are uniform s_loads (K$).
//  - quad-reduce hsum via __shfl_xor 1,2; all 4 lanes redundantly run the
//    tiny tail (msg/GN) - intra-wave redundancy costs the same wave cycles.
//  - lrelu-acc: sum += max(x,.2x) == sum += .6x + .4|x| (2 FMA, free |.|).

constexpr int DD  = 6;
constexpr int KK  = 16;
constexpr int CIN = 13;
constexpr float EPSV = 1e-5f;

__global__ __launch_bounds__(256, 5) void atom_mp(
    const float* __restrict__ dist,   // [P, K]
    const float* __restrict__ at,     // [P, K, D]
    const float* __restrict__ W1,     // [3, CIN, CIN]
    const float* __restrict__ b1,     // [3, CIN]
    const float* __restrict__ W2,     // [3, CIN, D]
    const float* __restrict__ b2,     // [3, D]
    const float* __restrict__ gw,     // [3, D]
    const float* __restrict__ gb,     // [3, D]
    float* __restrict__ out,          // [P, D]
    int P)
{
    int t = blockIdx.x * 256 + threadIdx.x;
    int p = t >> 2;      // point index
    int h = t & 3;       // neighbor quarter (4 neighbors each)
    if (p >= P) return;  // grid divides exactly; kept for safety

    // ---- 28 input floats into registers (one pass, 7 dwordx4 loads) ----
    float a[4 * DD];     // 4 neighbors x 6 feats
    float dq[4];
    {
        const float4* ga = reinterpret_cast<const float4*>(
            at + (long)p * (KK * DD) + h * (4 * DD));
        #pragma unroll
        for (int i = 0; i < 6; ++i) {
            float4 q = ga[i];
            a[4 * i + 0] = q.x; a[4 * i + 1] = q.y;
            a[4 * i + 2] = q.z; a[4 * i + 3] = q.w;
        }
        float4 qd = *reinterpret_cast<const float4*>(dist + (long)p * KK + h * 4);
        dq[0] = qd.x; dq[1] = qd.y; dq[2] = qd.z; dq[3] = qd.w;
    }

    float pe[DD] = {1.f, 1.f, 1.f, 1.f, 1.f, 1.f};

    #pragma unroll 1   // rolled layer loop keeps body (~750 instrs) in I$
    for (int L = 0; L < 3; ++L) {
        const float* w1  = W1 + L * CIN * CIN;
        const float* w2  = W2 + L * CIN * DD;
        const float* bb1 = b1 + L * CIN;
        const float* bb2 = b2 + L * DD;
        const float* gwp = gw + L * DD;
        const float* gbp = gb + L * DD;

        float hs[CIN];

        // d-outer, k-inner: 4 accumulators live, weights via uniform s_load
        #pragma unroll
        for (int d = 0; d < CIN; ++d) {
            float base = bb1[d];
            #pragma unroll
            for (int c = 0; c < DD; ++c)
                base = fmaf(pe[c], w1[c * CIN + d], base);

            float acc[4];
            float w0 = w1[6 * CIN + d];
            #pragma unroll
            for (int k = 0; k < 4; ++k)
                acc[k] = fmaf(a[6 * k], w0, base);
            #pragma unroll
            for (int j = 1; j < 6; ++j) {
                float w = w1[(6 + j) * CIN + d];
                #pragma unroll
                for (int k = 0; k < 4; ++k)
                    acc[k] = fmaf(a[6 * k + j], w, acc[k]);
            }
            {
                float w = w1[12 * CIN + d];
                #pragma unroll
                for (int k = 0; k < 4; ++k)
                    acc[k] = fmaf(dq[k], w, acc[k]);
            }
            // sum_k lrelu(acc[k]) = sum_k 0.6*acc + 0.4*|acc|
            float s = 0.f;
            #pragma unroll
            for (int k = 0; k < 4; ++k) {
                s = fmaf(0.6f, acc[k], s);
                s = fmaf(0.4f, __builtin_fabsf(acc[k]), s);
            }
            hs[d] = s;
        }

        // quad-reduce over the 4 threads of this point
        #pragma unroll
        for (int d = 0; d < CIN; ++d) {
            float v = hs[d];
            v += __shfl_xor(v, 1, 64);
            v += __shfl_xor(v, 2, 64);
            hs[d] = v;
        }

        // msg = hsum @ W2 + 16*b2   (all 4 lanes, redundantly)
        float msg[DD];
        #pragma unroll
        for (int d = 0; d < DD; ++d) {
            float m = 16.f * bb2[d];
            #pragma unroll
            for (int c = 0; c < CIN; ++c)
                m = fmaf(hs[c], w2[c * DD + d], m);
            msg[d] = m;
        }

        // GroupNorm(2 groups of 3) + affine + lrelu, residual add
        #pragma unroll
        for (int g = 0; g < 2; ++g) {
            float m0 = msg[3 * g], m1 = msg[3 * g + 1], m2 = msg[3 * g + 2];
            float mu = (m0 + m1 + m2) * (1.f / 3.f);
            float d0 = m0 - mu, d1 = m1 - mu, d2 = m2 - mu;
            float var = (d0 * d0 + d1 * d1 + d2 * d2) * (1.f / 3.f);
            float rs = rsqrtf(var + EPSV);
            float dv[3] = {d0, d1, d2};
            #pragma unroll
            for (int c = 0; c < 3; ++c) {
                int ch = 3 * g + c;
                float xn = fmaf(dv[c] * rs, gwp[ch], gbp[ch]);
                pe[ch] = fmaf(0.6f, xn, pe[ch]);
                pe[ch] = fmaf(0.4f, __builtin_fabsf(xn), pe[ch]);
            }
        }
    }

    // store: lanes h=0,1,2 of each quad write one float2 (6 floats total)
    if (h < 3) {
        float x = (h == 0) ? pe[0] : (h == 1) ? pe[2] : pe[4];
        float y = (h == 0) ? pe[1] : (h == 1) ? pe[3] : pe[5];
        *reinterpret_cast<float2*>(out + (long)p * DD + 2 * h) = make_float2(x, y);
    }
}

extern "C" void kernel_launch(void* const* d_in, const int* in_sizes, int n_in,
                              void* d_out, int out_size, void* d_ws, size_t ws_size,
                              hipStream_t stream) {
    const float* dist = (const float*)d_in[0];
    const float* at   = (const float*)d_in[1];
    const float* W1   = (const float*)d_in[2];
    const float* b1   = (const float*)d_in[3];
    const float* W2   = (const float*)d_in[4];
    const float* b2   = (const float*)d_in[5];
    const float* gw   = (const float*)d_in[6];
    const float* gb   = (const float*)d_in[7];
    float* out = (float*)d_out;

    int P = in_sizes[0] / KK;            // dist is [P, K]
    long threads_total = 4L * P;
    int blocks = (int)((threads_total + 255) / 256);
    atom_mp<<<blocks, 256, 0, stream>>>(dist, at, W1, b1, W2, b2, gw, gb, out, P);
}